// Round 12
// baseline (596.154 us; speedup 1.0000x reference)
//
#include <hip/hip_runtime.h>
#include <hip/hip_cooperative_groups.h>
#include <math.h>

namespace cg = cooperative_groups;

#define N_NODES 10000
#define N_EDGES 320000
#define IN_FEATS 256
#define N_HEADS 4
#define N_UNITS 64
#define OUT_FEATS 47
#define NEG_SLOPE 0.2f
#define MAX_GRID 512

typedef __attribute__((ext_vector_type(8))) short bf16x8;
typedef __attribute__((ext_vector_type(4))) float f32x4;

__device__ __forceinline__ float wave_reduce_sum(float v) {
#pragma unroll
  for (int s = 32; s > 0; s >>= 1) v += __shfl_down(v, s, 64);
  return __shfl(v, 0, 64);
}
__device__ __forceinline__ float wave_reduce_max(float v) {
#pragma unroll
  for (int s = 32; s > 0; s >>= 1) v = fmaxf(v, __shfl_down(v, s, 64));
  return __shfl(v, 0, 64);
}

__device__ __forceinline__ float lrelu_exp(float s) {
  s = (s > 0.f) ? s : NEG_SLOPE * s;
  return expf(s);
}

// fp32 -> bf16 round-to-nearest-even
__device__ __forceinline__ unsigned f2bf(float f) {
  unsigned u = __float_as_uint(f);
  return (u + 0x7FFFu + ((u >> 16) & 1u)) >> 16;
}

struct GatParams {
  const float* features;
  const int* src;
  const int* dst;
  const float* W1;
  const float* al1;
  const float* ar1;
  const float* W2;
  const float* al2;
  const float* ar2;
  float* out;
  unsigned short* feat1h;
  unsigned short* h2h;
  float* el1;
  float* er1;
  unsigned short* feat2ph;
  float* el2;
  float* er2;
  unsigned short* W1f;
  unsigned short* W2f;
  float* wa;
  float* wb;
  int* deg;
  int* cursor;
  int* offsets;
  int* src_csr;
  int* blocksum;
  int* blockpref;
};

// Single cooperative kernel: all phases separated by grid.sync().
// deg must be zeroed before launch (hipMemsetAsync).
__global__ __launch_bounds__(256, 2) void mega_kernel(GatParams P) {
  __shared__ __align__(16) char smem[57344];
  cg::grid_group grid = cg::this_grid();
  int b = blockIdx.x;
  int G = gridDim.x;
  int t = threadIdx.x;
  int lane = t & 63;
  int w = t >> 6;
  int quad = lane >> 4;

  // ================= P0: W1/W2 fragment packs + wa/wb + deg count =================
  for (int o = b * 256 + t; o < 65536; o += G * 256) {
    int j = o & 7;
    int l = (o >> 3) & 63;
    int r = o >> 9;
    int ks = r & 7;
    int ntg = r >> 3;
    int k = ks * 32 + (l >> 4) * 8 + j;
    int n = ntg * 16 + (l & 15);
    P.W1f[o] = (unsigned short)f2bf(P.W1[k * 256 + n]);
  }
  for (int o = b * 256 + t; o < 12288; o += G * 256) {
    int j = o & 7;
    int l = (o >> 3) & 63;
    int r = o >> 9;
    int ks = r & 7;
    int ntg = r >> 3;
    int k = ks * 32 + (l >> 4) * 8 + j;
    int n = ntg * 16 + (l & 15);
    P.W2f[o] = (n < OUT_FEATS) ? (unsigned short)f2bf(P.W2[k * OUT_FEATS + n]) : 0;
  }
  if (b == 0) {
    float a = 0.f, r = 0.f;
    for (int c = 0; c < OUT_FEATS; ++c) {
      float wv = P.W2[t * OUT_FEATS + c];
      a += wv * P.al2[c];
      r += wv * P.ar2[c];
    }
    P.wa[t] = a;
    P.wb[t] = r;
  }
  for (int e = b * 256 + t; e < N_EDGES; e += G * 256) atomicAdd(&P.deg[P.dst[e]], 1);
  grid.sync();

  // ================= P1: scan partials (wave 0) + gemm1 tiles =================
  int chunk = (N_NODES + G - 1) / G;  // <= 64 for G >= 157
  int nstart = b * chunk;
  int ncnt = N_NODES - nstart;
  if (ncnt < 0) ncnt = 0;
  if (ncnt > chunk) ncnt = chunk;
  if (t < 64) {
    int v = (t < ncnt) ? P.deg[nstart + t] : 0;
#pragma unroll
    for (int s = 32; s > 0; s >>= 1) v += __shfl_down(v, s, 64);
    if (t == 0) P.blocksum[b] = v;
  }

  {
    unsigned short* ldsA = (unsigned short*)smem;                    // 16 KB
    unsigned short* ldsBb[2] = {(unsigned short*)(smem + 16384),
                                (unsigned short*)(smem + 32768)};    // 2 x 16 KB
    float* ldsC = (float*)(smem + 16384);                            // 32 KB (reuse B)
    for (int tile = b; tile < 313; tile += G) {
      __syncthreads();
      int n0 = tile * 32;
      const float4* feat4 = (const float4*)P.features;
#pragma unroll
      for (int i = 0; i < 8; ++i) {
        int idx = i * 256 + t;
        int m = idx >> 6;
        int kb4 = idx & 63;
        float4 f = make_float4(0.f, 0.f, 0.f, 0.f);
        if (n0 + m < N_NODES) f = feat4[(size_t)(n0 + m) * 64 + kb4];
        unsigned u0 = f2bf(f.x) | (f2bf(f.y) << 16);
        unsigned u1 = f2bf(f.z) | (f2bf(f.w) << 16);
        int kb = kb4 >> 1;
        int di = m * 256 + ((kb ^ (m & 7)) << 3) + ((kb4 & 1) << 2);
        *(uint2*)&ldsA[di] = make_uint2(u0, u1);
      }
      const uint4* W1f4 = (const uint4*)P.W1f;
      uint4 pb[4];
#pragma unroll
      for (int it = 0; it < 4; ++it) {
        int ci = it * 256 + t;
        pb[it] = W1f4[((ci >> 6) * 8 + 0) * 64 + (ci & 63)];
      }
#pragma unroll
      for (int it = 0; it < 4; ++it) ((uint4*)ldsBb[0])[it * 256 + t] = pb[it];
      __syncthreads();

      f32x4 acc[2][4];
#pragma unroll
      for (int mt = 0; mt < 2; ++mt)
#pragma unroll
        for (int nt = 0; nt < 4; ++nt) acc[mt][nt] = 0.f;

      for (int ks = 0; ks < 8; ++ks) {
        if (ks < 7) {
#pragma unroll
          for (int it = 0; it < 4; ++it) {
            int ci = it * 256 + t;
            pb[it] = W1f4[((ci >> 6) * 8 + ks + 1) * 64 + (ci & 63)];
          }
        }
        unsigned short* B = ldsBb[ks & 1];
        bf16x8 af[2];
#pragma unroll
        for (int mt = 0; mt < 2; ++mt) {
          int m = mt * 16 + (lane & 15);
          int kb = ks * 4 + quad;
          af[mt] = *(const bf16x8*)&ldsA[m * 256 + ((kb ^ (m & 7)) << 3)];
        }
#pragma unroll
        for (int nt = 0; nt < 4; ++nt) {
          bf16x8 bf = *(const bf16x8*)&B[((w * 4 + nt) * 64 + lane) * 8];
#pragma unroll
          for (int mt = 0; mt < 2; ++mt)
            acc[mt][nt] =
                __builtin_amdgcn_mfma_f32_16x16x32_bf16(af[mt], bf, acc[mt][nt], 0, 0, 0);
        }
        if (ks < 7) {
          unsigned short* Bn = ldsBb[(ks + 1) & 1];
#pragma unroll
          for (int it = 0; it < 4; ++it) ((uint4*)Bn)[it * 256 + t] = pb[it];
        }
        __syncthreads();
      }

#pragma unroll
      for (int mt = 0; mt < 2; ++mt)
#pragma unroll
        for (int nt = 0; nt < 4; ++nt)
#pragma unroll
          for (int r = 0; r < 4; ++r)
            ldsC[(mt * 16 + quad * 4 + r) * 256 + w * 64 + nt * 16 + (lane & 15)] =
                acc[mt][nt][r];
      __syncthreads();

      int c = lane * 4;
      int r0 = w * 8;
      float4 alv = ((const float4*)P.al1)[lane];
      float4 arv = ((const float4*)P.ar1)[lane];
#pragma unroll
      for (int i = 0; i < 8; ++i) {
        int rl = r0 + i;
        int row = n0 + rl;
        float4 a = *(const float4*)&ldsC[rl * 256 + c];
        bool valid = row < N_NODES;
        if (valid) {
          unsigned p0 = f2bf(a.x) | (f2bf(a.y) << 16);
          unsigned p1 = f2bf(a.z) | (f2bf(a.w) << 16);
          *(uint2*)&P.feat1h[(size_t)row * 256 + c] = make_uint2(p0, p1);
        }
        float el = a.x * alv.x + a.y * alv.y + a.z * alv.z + a.w * alv.w;
        float er = a.x * arv.x + a.y * arv.y + a.z * arv.z + a.w * arv.w;
#pragma unroll
        for (int s = 8; s > 0; s >>= 1) {
          el += __shfl_down(el, s, 16);
          er += __shfl_down(er, s, 16);
        }
        if ((lane & 15) == 0 && valid) {
          P.el1[row * 4 + (lane >> 4)] = el;
          P.er1[row * 4 + (lane >> 4)] = er;
        }
      }
    }
  }
  grid.sync();

  // ================= P2: block 0 exclusive-scans blocksum[0..G) =================
  if (b == 0) {
    int* lds = (int*)smem;
    int s0 = (2 * t < G) ? P.blocksum[2 * t] : 0;
    int s1 = (2 * t + 1 < G) ? P.blocksum[2 * t + 1] : 0;
    lds[t] = s0 + s1;
    __syncthreads();
    for (int s = 1; s < 256; s <<= 1) {
      int v = (t >= s) ? lds[t - s] : 0;
      __syncthreads();
      lds[t] += v;
      __syncthreads();
    }
    int pairpref = (t == 0) ? 0 : lds[t - 1];
    if (2 * t < G) P.blockpref[2 * t] = pairpref;
    if (2 * t + 1 < G) P.blockpref[2 * t + 1] = pairpref + s0;
    if (t == 255) P.offsets[N_NODES] = lds[255];
  }
  grid.sync();

  // ================= P3: offsets/cursor for this block's node chunk =================
  {
    int* ldsdeg = (int*)smem;
    if (t < ncnt) ldsdeg[t] = P.deg[nstart + t];
    __syncthreads();
    if (t == 0 && ncnt > 0) {
      int base = P.blockpref[b];
      for (int i = 0; i < ncnt; ++i) {
        int d0 = ldsdeg[i];
        ldsdeg[i] = base;
        base += d0;
      }
    }
    __syncthreads();
    if (t < ncnt) {
      int o = ldsdeg[t];
      P.offsets[nstart + t] = o;
      P.cursor[nstart + t] = o;
    }
  }
  grid.sync();

  // ================= P4: CSR fill =================
  for (int e = b * 256 + t; e < N_EDGES; e += G * 256) {
    int p = atomicAdd(&P.cursor[P.dst[e]], 1);
    P.src_csr[p] = P.src[e];
  }
  grid.sync();

  // ================= P5: agg1 (node-parallel, grid-stride) =================
  {
    float4* lds_s4 = (float4*)smem;                      // 4 KB
    int* lds_sn = (int*)(smem + 4096);                   // 1 KB
    float* ldsacc = (float*)(smem + 5120);               // 4 KB  [4][256]
    float* ldssum = (float*)(smem + 9216);               // 64 B  [4][4]
    float* ldse = (float*)(smem + 9280);                 // 16 B
    float* ldsr = (float*)(smem + 9296);                 // 16 B
    int half = lane >> 5;
    int hl = lane & 31;
    int head = hl >> 3;
    for (int n = b; n < N_NODES; n += G) {
      __syncthreads();
      int off = P.offsets[n];
      int deg = P.offsets[n + 1] - off;
      float4 er4 = ((const float4*)P.er1)[n];

      float acc[8];
#pragma unroll
      for (int r = 0; r < 8; ++r) acc[r] = 0.f;
      float4 esum = {0.f, 0.f, 0.f, 0.f};

      for (int c0 = 0; c0 < deg; c0 += 256) {
        int cnt = min(256, deg - c0);
        if (t < cnt) {
          int sn = P.src_csr[off + c0 + t];
          float4 el = ((const float4*)P.el1)[sn];
          lds_sn[t] = sn;
          lds_s4[t] = make_float4(lrelu_exp(el.x + er4.x), lrelu_exp(el.y + er4.y),
                                  lrelu_exp(el.z + er4.z), lrelu_exp(el.w + er4.w));
        }
        __syncthreads();
        for (int p = w * 2 + half; p < cnt; p += 8) {
          int sn = lds_sn[p];
          float4 a4 = lds_s4[p];
          uint4 u = *(const uint4*)&P.feat1h[(size_t)sn * 256 + hl * 8];
          float aw = (head == 0) ? a4.x : (head == 1) ? a4.y : (head == 2) ? a4.z : a4.w;
          acc[0] += aw * __uint_as_float(u.x << 16);
          acc[1] += aw * __uint_as_float(u.x & 0xFFFF0000u);
          acc[2] += aw * __uint_as_float(u.y << 16);
          acc[3] += aw * __uint_as_float(u.y & 0xFFFF0000u);
          acc[4] += aw * __uint_as_float(u.z << 16);
          acc[5] += aw * __uint_as_float(u.z & 0xFFFF0000u);
          acc[6] += aw * __uint_as_float(u.w << 16);
          acc[7] += aw * __uint_as_float(u.w & 0xFFFF0000u);
          esum.x += a4.x;
          esum.y += a4.y;
          esum.z += a4.z;
          esum.w += a4.w;
        }
        __syncthreads();
      }
#pragma unroll
      for (int r = 0; r < 8; ++r) acc[r] += __shfl_down(acc[r], 32, 64);
      esum.x += __shfl_down(esum.x, 32, 64);
      esum.y += __shfl_down(esum.y, 32, 64);
      esum.z += __shfl_down(esum.z, 32, 64);
      esum.w += __shfl_down(esum.w, 32, 64);
      if (half == 0) {
        *(float4*)&ldsacc[w * 256 + hl * 8] = make_float4(acc[0], acc[1], acc[2], acc[3]);
        *(float4*)&ldsacc[w * 256 + hl * 8 + 4] = make_float4(acc[4], acc[5], acc[6], acc[7]);
      }
      if (lane == 0) *(float4*)&ldssum[w * 4] = esum;
      __syncthreads();

      float tot = ldsacc[t] + ldsacc[256 + t] + ldsacc[512 + t] + ldsacc[768 + t];
      int h = t >> 6;
      float denom = ldssum[h] + ldssum[4 + h] + ldssum[8 + h] + ldssum[12 + h];
      float val = tot / fmaxf(denom, 1e-9f);
      val = (val > 0.f) ? val : expm1f(val);  // ELU

      float elp = val * P.wa[t];
      float erp = val * P.wb[t];
#pragma unroll
      for (int s = 32; s > 0; s >>= 1) {
        elp += __shfl_down(elp, s, 64);
        erp += __shfl_down(erp, s, 64);
      }
      if (lane == 0) {
        ldse[w] = elp;
        ldsr[w] = erp;
      }
      float vhi = __shfl_down(val, 1, 64);
      if (!(t & 1)) *(unsigned*)&P.h2h[(size_t)n * 256 + t] = f2bf(val) | (f2bf(vhi) << 16);
      __syncthreads();
      if (t == 0) {
        P.el2[n] = ldse[0] + ldse[1] + ldse[2] + ldse[3];
        P.er2[n] = ldsr[0] + ldsr[1] + ldsr[2] + ldsr[3];
      }
    }
  }
  grid.sync();

  // ================= P6: gemm2 (64-row tiles, grid-stride) =================
  {
    unsigned short* ldsA = (unsigned short*)smem;            // 32 KB
    unsigned short* ldsB = (unsigned short*)(smem + 32768);  // 24 KB
    float* ldsC = (float*)(smem + 32768);                    // 12 KB (reuse B)
    for (int tile = b; tile < (N_NODES + 63) / 64; tile += G) {
      __syncthreads();
      int n0 = tile * 64;
#pragma unroll
      for (int i = 0; i < 8; ++i) {
        int idx = i * 256 + t;
        int m = idx >> 5;
        int kb = idx & 31;
        uint4 u = make_uint4(0, 0, 0, 0);
        if (n0 + m < N_NODES) u = ((const uint4*)(P.h2h + (size_t)(n0 + m) * 256))[kb];
        *(uint4*)&ldsA[m * 256 + ((kb ^ (m & 7)) << 3)] = u;
      }
      const uint4* Bg = (const uint4*)P.W2f;
#pragma unroll
      for (int i = 0; i < 6; ++i) ((uint4*)ldsB)[i * 256 + t] = Bg[i * 256 + t];
      __syncthreads();

      f32x4 acc[3];
#pragma unroll
      for (int nt = 0; nt < 3; ++nt) acc[nt] = 0.f;
#pragma unroll
      for (int ks = 0; ks < 8; ++ks) {
        int m = w * 16 + (lane & 15);
        int kb = ks * 4 + quad;
        bf16x8 af = *(const bf16x8*)&ldsA[m * 256 + ((kb ^ (m & 7)) << 3)];
#pragma unroll
        for (int nt = 0; nt < 3; ++nt) {
          bf16x8 bf = *(const bf16x8*)&ldsB[((nt * 8 + ks) * 64 + lane) * 8];
          acc[nt] = __builtin_amdgcn_mfma_f32_16x16x32_bf16(af, bf, acc[nt], 0, 0, 0);
        }
      }
      __syncthreads();

#pragma unroll
      for (int nt = 0; nt < 3; ++nt)
#pragma unroll
        for (int r = 0; r < 4; ++r)
          ldsC[(w * 16 + quad * 4 + r) * 48 + nt * 16 + (lane & 15)] = acc[nt][r];
      __syncthreads();

#pragma unroll
      for (int i = 0; i < 6; ++i) {
        int idx = i * 256 + t;
        int row = idx / 24;
        int c2 = idx - row * 24;
        int grow = n0 + row;
        if (grow < N_NODES) {
          unsigned u =
              f2bf(ldsC[row * 48 + c2 * 2]) | (f2bf(ldsC[row * 48 + c2 * 2 + 1]) << 16);
          ((unsigned*)P.feat2ph)[(size_t)grow * 24 + c2] = u;
        }
      }
    }
  }
  grid.sync();

  // ================= P7: agg2 + log_softmax (node-parallel, grid-stride) =================
  {
    float* lds_s = (float*)smem;           // 1 KB
    int* lds_sn = (int*)(smem + 1024);     // 1 KB
    float* ldsacc = (float*)(smem + 2048); // [4][48]
    float* ldssum = (float*)(smem + 2816); // [4]
    int half = lane >> 5;
    int hl = lane & 31;
    for (int n = b; n < N_NODES; n += G) {
      __syncthreads();
      int off = P.offsets[n];
      int deg = P.offsets[n + 1] - off;
      float ern = P.er2[n];

      float a0 = 0.f, a1 = 0.f;
      float esum = 0.f;
      for (int c0 = 0; c0 < deg; c0 += 256) {
        int cnt = min(256, deg - c0);
        if (t < cnt) {
          int sn = P.src_csr[off + c0 + t];
          lds_sn[t] = sn;
          lds_s[t] = lrelu_exp(P.el2[sn] + ern);
        }
        __syncthreads();
        for (int p = w * 2 + half; p < cnt; p += 8) {
          int sn = lds_sn[p];
          float a = lds_s[p];
          if (hl < 24) {
            unsigned u = ((const unsigned*)P.feat2ph)[(size_t)sn * 24 + hl];
            a0 += a * __uint_as_float(u << 16);
            a1 += a * __uint_as_float(u & 0xFFFF0000u);
          }
          esum += a;
        }
        __syncthreads();
      }
      a0 += __shfl_down(a0, 32, 64);
      a1 += __shfl_down(a1, 32, 64);
      esum += __shfl_down(esum, 32, 64);
      if (half == 0 && hl < 24) {
        ldsacc[w * 48 + hl * 2] = a0;
        ldsacc[w * 48 + hl * 2 + 1] = a1;
      }
      if (lane == 0) ldssum[w] = esum;  // lane0 = wave partial (no wave-reduce!)
      __syncthreads();

      if (t < 64) {
        float denom = ldssum[0] + ldssum[1] + ldssum[2] + ldssum[3];
        float inv = 1.f / fmaxf(denom, 1e-9f);
        float logits = 0.f;
        if (t < OUT_FEATS)
          logits = (ldsacc[t] + ldsacc[48 + t] + ldsacc[96 + t] + ldsacc[144 + t]) * inv;
        float v = (t < OUT_FEATS) ? logits : -INFINITY;
        float mx = wave_reduce_max(v);
        float ex = (t < OUT_FEATS) ? expf(logits - mx) : 0.f;
        float s = wave_reduce_sum(ex);
        if (t < OUT_FEATS) P.out[n * OUT_FEATS + t] = logits - mx - logf(s);
      }
    }
  }
}

extern "C" void kernel_launch(void* const* d_in, const int* in_sizes, int n_in,
                              void* d_out, int out_size, void* d_ws, size_t ws_size,
                              hipStream_t stream) {
  char* ws = (char*)d_ws;
  size_t o = 0;
  auto alloc = [&](size_t bytes) {
    void* p = ws + o;
    o = (o + bytes + 255) & ~(size_t)255;
    return p;
  };
  GatParams P;
  P.features = (const float*)d_in[0];
  P.src = (const int*)d_in[1];
  P.dst = (const int*)d_in[2];
  P.W1 = (const float*)d_in[3];
  P.al1 = (const float*)d_in[4];
  P.ar1 = (const float*)d_in[5];
  P.W2 = (const float*)d_in[6];
  P.al2 = (const float*)d_in[7];
  P.ar2 = (const float*)d_in[8];
  P.out = (float*)d_out;
  P.feat1h = (unsigned short*)alloc((size_t)N_NODES * 256 * 2);
  P.h2h = (unsigned short*)alloc((size_t)N_NODES * 256 * 2);
  P.el1 = (float*)alloc((size_t)N_NODES * 4 * 4);
  P.er1 = (float*)alloc((size_t)N_NODES * 4 * 4);
  P.feat2ph = (unsigned short*)alloc((size_t)N_NODES * 48 * 2);
  P.el2 = (float*)alloc((size_t)N_NODES * 4);
  P.er2 = (float*)alloc((size_t)N_NODES * 4);
  P.W1f = (unsigned short*)alloc((size_t)256 * 256 * 2);
  P.W2f = (unsigned short*)alloc((size_t)256 * 48 * 2);
  P.wa = (float*)alloc(256 * 4);
  P.wb = (float*)alloc(256 * 4);
  P.deg = (int*)alloc((size_t)N_NODES * 4);
  P.cursor = (int*)alloc((size_t)N_NODES * 4);
  P.offsets = (int*)alloc((size_t)(N_NODES + 1) * 4);
  P.src_csr = (int*)alloc((size_t)N_EDGES * 4);
  P.blocksum = (int*)alloc((size_t)MAX_GRID * 4);
  P.blockpref = (int*)alloc((size_t)MAX_GRID * 4);

  hipMemsetAsync(P.deg, 0, (size_t)N_NODES * 4, stream);

  int maxB = 0;
  if (hipOccupancyMaxActiveBlocksPerMultiprocessor(&maxB, mega_kernel, 256, 0) != hipSuccess ||
      maxB < 1)
    maxB = 1;
  int grid = maxB * 256;  // 256 CUs on MI355X
  if (grid > MAX_GRID) grid = MAX_GRID;

  void* args[] = {(void*)&P};
  hipLaunchCooperativeKernel(mega_kernel, dim3(grid), dim3(256), args, 0, stream);
}

// Round 13
// 195.778 us; speedup vs baseline: 3.0451x; 3.0451x over previous
//
#include <hip/hip_runtime.h>
#include <math.h>

#define N_NODES 10000
#define N_EDGES 320000
#define IN_FEATS 256
#define N_HEADS 4
#define N_UNITS 64
#define OUT_FEATS 47
#define NEG_SLOPE 0.2f

typedef __attribute__((ext_vector_type(8))) short bf16x8;
typedef __attribute__((ext_vector_type(4))) float f32x4;

__device__ __forceinline__ float wave_reduce_sum(float v) {
#pragma unroll
  for (int s = 32; s > 0; s >>= 1) v += __shfl_down(v, s, 64);
  return __shfl(v, 0, 64);
}
__device__ __forceinline__ float wave_reduce_max(float v) {
#pragma unroll
  for (int s = 32; s > 0; s >>= 1) v = fmaxf(v, __shfl_down(v, s, 64));
  return __shfl(v, 0, 64);
}

__device__ __forceinline__ float lrelu_exp(float s) {
  s = (s > 0.f) ? s : NEG_SLOPE * s;
  return expf(s);
}

// fp32 -> bf16 round-to-nearest-even
__device__ __forceinline__ unsigned f2bf(float f) {
  unsigned u = __float_as_uint(f);
  return (u + 0x7FFFu + ((u >> 16) & 1u)) >> 16;
}

// ---------------- fused prep: deg count + W1/W2 packing + wa/wb ----------------
__global__ __launch_bounds__(256) void prep_kernel(
    const int* __restrict__ dst, int* __restrict__ deg,
    const float* __restrict__ W1, unsigned short* __restrict__ W1f,
    const float* __restrict__ W2, unsigned short* __restrict__ W2f,
    const float* __restrict__ al2, const float* __restrict__ ar2,
    float* __restrict__ wa, float* __restrict__ wb) {
  int b = blockIdx.x;
  int t = threadIdx.x;
  if (b < 1250) {
    int e = b * 256 + t;
    if (e < N_EDGES) atomicAdd(&deg[dst[e]], 1);
  } else if (b < 1250 + 256) {
    int o = (b - 1250) * 256 + t;  // 0..65535
    int j = o & 7;
    int lane = (o >> 3) & 63;
    int r = o >> 9;
    int ks = r & 7;
    int ntg = r >> 3;
    int k = ks * 32 + (lane >> 4) * 8 + j;
    int n = ntg * 16 + (lane & 15);
    W1f[o] = (unsigned short)f2bf(W1[k * 256 + n]);
  } else if (b < 1554) {
    int o = (b - 1506) * 256 + t;  // 0..12287
    int j = o & 7;
    int lane = (o >> 3) & 63;
    int r = o >> 9;  // 0..23
    int ks = r & 7;
    int ntg = r >> 3;  // 0..2
    int k = ks * 32 + (lane >> 4) * 8 + j;
    int n = ntg * 16 + (lane & 15);
    W2f[o] = (n < OUT_FEATS) ? (unsigned short)f2bf(W2[k * OUT_FEATS + n]) : 0;
  } else {
    float a = 0.f, r = 0.f;
    for (int c = 0; c < OUT_FEATS; ++c) {
      float w = W2[t * OUT_FEATS + c];
      a += w * al2[c];
      r += w * ar2[c];
    }
    wa[t] = a;
    wb[t] = r;
  }
}

// CSR fill: src_csr only (scores computed in-block inside agg kernels).
__global__ void fill_kernel(const int* __restrict__ src, const int* __restrict__ dst,
                            int* __restrict__ cursor, int* __restrict__ src_csr) {
  int e = blockIdx.x * blockDim.x + threadIdx.x;
  if (e >= N_EDGES) return;
  int p = atomicAdd(&cursor[dst[e]], 1);
  src_csr[p] = src[e];
}

// ---------------- Layer 1 GEMM (MFMA bf16) + fused scan (block 313) ----------------
__global__ __launch_bounds__(256) void gemm1_scan_kernel(
    const float* __restrict__ features, const unsigned short* __restrict__ W1f,
    const float* __restrict__ al1, const float* __restrict__ ar1,
    unsigned short* __restrict__ feat1h, float* __restrict__ el1, float* __restrict__ er1,
    const int* __restrict__ deg, int* __restrict__ offsets, int* __restrict__ cursor) {
  __shared__ __align__(16) char smem[49152];
  int t = threadIdx.x;

  if (blockIdx.x == 313) {  // ---- scan path ----
    int* partial = (int*)smem;
    const int chunk = (N_NODES + 255) / 256;  // 40
    int start = t * chunk;
    int end = min(start + chunk, N_NODES);
    int sum = 0;
    for (int i = start; i < end; ++i) sum += deg[i];
    partial[t] = sum;
    __syncthreads();
    for (int s = 1; s < 256; s <<= 1) {
      int v = (t >= s) ? partial[t - s] : 0;
      __syncthreads();
      partial[t] += v;
      __syncthreads();
    }
    int base = (t == 0) ? 0 : partial[t - 1];
    for (int i = start; i < end; ++i) {
      offsets[i] = base;
      cursor[i] = base;
      base += deg[i];
    }
    if (t == 0) offsets[N_NODES] = partial[255];
    return;
  }

  // ---- GEMM path ----
  unsigned short* ldsA = (unsigned short*)smem;                    // 16 KB
  unsigned short* ldsBbuf[2] = {(unsigned short*)(smem + 16384),
                                (unsigned short*)(smem + 32768)};  // 2 x 16 KB
  float* ldsC = (float*)(smem + 16384);                            // 32 KB (reuse B)

  int n0 = blockIdx.x * 32;
  int lane = t & 63;
  int w = t >> 6;
  int quad = lane >> 4;

  const float4* feat4 = (const float4*)features;
#pragma unroll
  for (int i = 0; i < 8; ++i) {
    int idx = i * 256 + t;
    int m = idx >> 6;
    int kb4 = idx & 63;
    float4 f = make_float4(0.f, 0.f, 0.f, 0.f);
    if (n0 + m < N_NODES) f = feat4[(size_t)(n0 + m) * 64 + kb4];
    unsigned u0 = f2bf(f.x) | (f2bf(f.y) << 16);
    unsigned u1 = f2bf(f.z) | (f2bf(f.w) << 16);
    int kb = kb4 >> 1;
    int di = m * 256 + ((kb ^ (m & 7)) << 3) + ((kb4 & 1) << 2);
    *(uint2*)&ldsA[di] = make_uint2(u0, u1);
  }

  const uint4* W1f4 = (const uint4*)W1f;
  uint4 pb[4];
#pragma unroll
  for (int it = 0; it < 4; ++it) {
    int ci = it * 256 + t;
    pb[it] = W1f4[((ci >> 6) * 8 + 0) * 64 + (ci & 63)];
  }
#pragma unroll
  for (int it = 0; it < 4; ++it) ((uint4*)ldsBbuf[0])[it * 256 + t] = pb[it];
  __syncthreads();

  f32x4 acc[2][4];
#pragma unroll
  for (int mt = 0; mt < 2; ++mt)
#pragma unroll
    for (int nt = 0; nt < 4; ++nt) acc[mt][nt] = 0.f;

  for (int ks = 0; ks < 8; ++ks) {
    if (ks < 7) {
#pragma unroll
      for (int it = 0; it < 4; ++it) {
        int ci = it * 256 + t;
        pb[it] = W1f4[((ci >> 6) * 8 + ks + 1) * 64 + (ci & 63)];
      }
    }
    unsigned short* B = ldsBbuf[ks & 1];
    bf16x8 af[2];
#pragma unroll
    for (int mt = 0; mt < 2; ++mt) {
      int m = mt * 16 + (lane & 15);
      int kb = ks * 4 + quad;
      af[mt] = *(const bf16x8*)&ldsA[m * 256 + ((kb ^ (m & 7)) << 3)];
    }
#pragma unroll
    for (int nt = 0; nt < 4; ++nt) {
      bf16x8 bf = *(const bf16x8*)&B[((w * 4 + nt) * 64 + lane) * 8];
#pragma unroll
      for (int mt = 0; mt < 2; ++mt)
        acc[mt][nt] = __builtin_amdgcn_mfma_f32_16x16x32_bf16(af[mt], bf, acc[mt][nt], 0, 0, 0);
    }
    if (ks < 7) {
      unsigned short* Bn = ldsBbuf[(ks + 1) & 1];
#pragma unroll
      for (int it = 0; it < 4; ++it) ((uint4*)Bn)[it * 256 + t] = pb[it];
    }
    __syncthreads();
  }

#pragma unroll
  for (int mt = 0; mt < 2; ++mt)
#pragma unroll
    for (int nt = 0; nt < 4; ++nt)
#pragma unroll
      for (int r = 0; r < 4; ++r)
        ldsC[(mt * 16 + quad * 4 + r) * 256 + w * 64 + nt * 16 + (lane & 15)] = acc[mt][nt][r];
  __syncthreads();

  int c = lane * 4;
  int r0 = w * 8;
  float4 alv = ((const float4*)al1)[lane];
  float4 arv = ((const float4*)ar1)[lane];
#pragma unroll
  for (int i = 0; i < 8; ++i) {
    int rl = r0 + i;
    int row = n0 + rl;
    float4 a = *(const float4*)&ldsC[rl * 256 + c];
    bool valid = row < N_NODES;
    if (valid) {
      unsigned p0 = f2bf(a.x) | (f2bf(a.y) << 16);
      unsigned p1 = f2bf(a.z) | (f2bf(a.w) << 16);
      *(uint2*)&feat1h[(size_t)row * 256 + c] = make_uint2(p0, p1);
    }
    float el = a.x * alv.x + a.y * alv.y + a.z * alv.z + a.w * alv.w;
    float er = a.x * arv.x + a.y * arv.y + a.z * arv.z + a.w * arv.w;
#pragma unroll
    for (int s = 8; s > 0; s >>= 1) {
      el += __shfl_down(el, s, 16);
      er += __shfl_down(er, s, 16);
    }
    if ((lane & 15) == 0 && valid) {
      el1[row * 4 + (lane >> 4)] = el;
      er1[row * 4 + (lane >> 4)] = er;
    }
  }
}

// ---------------- Layer 1 aggregate: in-block scores + bf16 gather ----------------
// Phase A (per 256-edge tile): thread t computes edge t's 4-head exp-scores into
// LDS (edge-parallel — NOT per-lane redundant). Phase B: half-wave per edge
// (2 edges/wave-iter), scores + src ids from LDS.
__global__ __launch_bounds__(256) void agg1_kernel(
    const int* __restrict__ src_csr, const int* __restrict__ offsets,
    const unsigned short* __restrict__ feat1h, const float* __restrict__ el1,
    const float* __restrict__ er1, const float* __restrict__ wa,
    const float* __restrict__ wb, unsigned short* __restrict__ h2h,
    float* __restrict__ el2, float* __restrict__ er2) {
  __shared__ float4 lds_s4[256];
  __shared__ int lds_sn[256];
  __shared__ float ldsacc[4][256];
  __shared__ float ldssum[4][4];
  __shared__ float ldse[4], ldsr[4];
  int n = blockIdx.x;
  int t = threadIdx.x;
  int w = t >> 6;
  int lane = t & 63;
  int half = lane >> 5;
  int hl = lane & 31;
  int off = offsets[n];
  int deg = offsets[n + 1] - off;
  int head = hl >> 3;
  float4 er4 = ((const float4*)er1)[n];

  float acc[8];
#pragma unroll
  for (int r = 0; r < 8; ++r) acc[r] = 0.f;
  float4 esum = {0.f, 0.f, 0.f, 0.f};

  for (int c0 = 0; c0 < deg; c0 += 256) {
    int cnt = min(256, deg - c0);
    if (t < cnt) {
      int sn = src_csr[off + c0 + t];
      float4 el = ((const float4*)el1)[sn];  // 160 KB L2-hot table
      lds_sn[t] = sn;
      lds_s4[t] = make_float4(lrelu_exp(el.x + er4.x), lrelu_exp(el.y + er4.y),
                              lrelu_exp(el.z + er4.z), lrelu_exp(el.w + er4.w));
    }
    __syncthreads();
    for (int p = w * 2 + half; p < cnt; p += 8) {
      int sn = lds_sn[p];     // LDS broadcast
      float4 a4 = lds_s4[p];  // LDS broadcast
      uint4 u = *(const uint4*)&feat1h[(size_t)sn * 256 + hl * 8];  // 512B/edge
      float aw = (head == 0) ? a4.x : (head == 1) ? a4.y : (head == 2) ? a4.z : a4.w;
      acc[0] += aw * __uint_as_float(u.x << 16);
      acc[1] += aw * __uint_as_float(u.x & 0xFFFF0000u);
      acc[2] += aw * __uint_as_float(u.y << 16);
      acc[3] += aw * __uint_as_float(u.y & 0xFFFF0000u);
      acc[4] += aw * __uint_as_float(u.z << 16);
      acc[5] += aw * __uint_as_float(u.z & 0xFFFF0000u);
      acc[6] += aw * __uint_as_float(u.w << 16);
      acc[7] += aw * __uint_as_float(u.w & 0xFFFF0000u);
      esum.x += a4.x;
      esum.y += a4.y;
      esum.z += a4.z;
      esum.w += a4.w;
    }
    __syncthreads();
  }
#pragma unroll
  for (int r = 0; r < 8; ++r) acc[r] += __shfl_down(acc[r], 32, 64);
  esum.x += __shfl_down(esum.x, 32, 64);
  esum.y += __shfl_down(esum.y, 32, 64);
  esum.z += __shfl_down(esum.z, 32, 64);
  esum.w += __shfl_down(esum.w, 32, 64);
  if (half == 0) {
    *(float4*)&ldsacc[w][hl * 8] = make_float4(acc[0], acc[1], acc[2], acc[3]);
    *(float4*)&ldsacc[w][hl * 8 + 4] = make_float4(acc[4], acc[5], acc[6], acc[7]);
  }
  if (lane == 0) *(float4*)&ldssum[w][0] = esum;  // halves combined; lane0 = wave partial
  __syncthreads();

  float tot = ldsacc[0][t] + ldsacc[1][t] + ldsacc[2][t] + ldsacc[3][t];
  int h = t >> 6;
  float denom = ldssum[0][h] + ldssum[1][h] + ldssum[2][h] + ldssum[3][h];
  float val = tot / fmaxf(denom, 1e-9f);
  val = (val > 0.f) ? val : expm1f(val);  // ELU

  float elp = val * wa[t];
  float erp = val * wb[t];
#pragma unroll
  for (int s = 32; s > 0; s >>= 1) {
    elp += __shfl_down(elp, s, 64);
    erp += __shfl_down(erp, s, 64);
  }
  if (lane == 0) {
    ldse[w] = elp;
    ldsr[w] = erp;
  }
  float vhi = __shfl_down(val, 1, 64);
  if (!(t & 1)) *(unsigned*)&h2h[(size_t)n * 256 + t] = f2bf(val) | (f2bf(vhi) << 16);
  __syncthreads();
  if (t == 0) {
    el2[n] = ldse[0] + ldse[1] + ldse[2] + ldse[3];
    er2[n] = ldsr[0] + ldsr[1] + ldsr[2] + ldsr[3];
  }
}

// ---------------- Layer 2 GEMM (MFMA bf16): feat2ph(bf16, 48-padded) = h2h @ W2 ------
__global__ __launch_bounds__(256) void gemm2_kernel(
    const unsigned short* __restrict__ h2h, const unsigned short* __restrict__ W2f,
    unsigned short* __restrict__ feat2ph) {
  __shared__ __align__(16) char smem[32768 + 24576];
  unsigned short* ldsA = (unsigned short*)smem;            // 32 KB
  unsigned short* ldsB = (unsigned short*)(smem + 32768);  // 24 KB
  float* ldsC = (float*)(smem + 32768);                    // 12 KB (reuse B)

  int t = threadIdx.x;
  int n0 = blockIdx.x * 64;
  int lane = t & 63;
  int w = t >> 6;
  int quad = lane >> 4;

#pragma unroll
  for (int i = 0; i < 8; ++i) {
    int idx = i * 256 + t;  // 0..2047 uint4s
    int m = idx >> 5;
    int kb = idx & 31;
    uint4 u = make_uint4(0, 0, 0, 0);
    if (n0 + m < N_NODES) u = ((const uint4*)(h2h + (size_t)(n0 + m) * 256))[kb];
    *(uint4*)&ldsA[m * 256 + ((kb ^ (m & 7)) << 3)] = u;
  }
  const uint4* Bg = (const uint4*)W2f;
#pragma unroll
  for (int i = 0; i < 6; ++i) ((uint4*)ldsB)[i * 256 + t] = Bg[i * 256 + t];
  __syncthreads();

  f32x4 acc[3];
#pragma unroll
  for (int nt = 0; nt < 3; ++nt) acc[nt] = 0.f;

#pragma unroll
  for (int ks = 0; ks < 8; ++ks) {
    int m = w * 16 + (lane & 15);
    int kb = ks * 4 + quad;
    bf16x8 af = *(const bf16x8*)&ldsA[m * 256 + ((kb ^ (m & 7)) << 3)];
#pragma unroll
    for (int nt = 0; nt < 3; ++nt) {
      bf16x8 bf = *(const bf16x8*)&ldsB[((nt * 8 + ks) * 64 + lane) * 8];
      acc[nt] = __builtin_amdgcn_mfma_f32_16x16x32_bf16(af, bf, acc[nt], 0, 0, 0);
    }
  }
  __syncthreads();  // all B reads done before C overwrites

#pragma unroll
  for (int nt = 0; nt < 3; ++nt)
#pragma unroll
    for (int r = 0; r < 4; ++r)
      ldsC[(w * 16 + quad * 4 + r) * 48 + nt * 16 + (lane & 15)] = acc[nt][r];
  __syncthreads();

#pragma unroll
  for (int i = 0; i < 6; ++i) {
    int idx = i * 256 + t;  // 0..1535
    int row = idx / 24;
    int c2 = idx - row * 24;
    int grow = n0 + row;
    if (grow < N_NODES) {
      unsigned u = f2bf(ldsC[row * 48 + c2 * 2]) | (f2bf(ldsC[row * 48 + c2 * 2 + 1]) << 16);
      ((unsigned*)feat2ph)[(size_t)grow * 24 + c2] = u;
    }
  }
}

// ---------------- Layer 2 aggregate + fused scores + log_softmax ----------------
__global__ __launch_bounds__(256) void agg2_kernel(
    const int* __restrict__ src_csr, const int* __restrict__ offsets,
    const unsigned short* __restrict__ feat2ph, const float* __restrict__ el2,
    const float* __restrict__ er2, float* __restrict__ out) {
  __shared__ float lds_s[256];
  __shared__ int lds_sn[256];
  __shared__ float ldsacc[4][48];
  __shared__ float ldssum[4];
  int n = blockIdx.x;
  int t = threadIdx.x;
  int w = t >> 6;
  int lane = t & 63;
  int half = lane >> 5;
  int hl = lane & 31;
  int off = offsets[n];
  int deg = offsets[n + 1] - off;
  float ern = er2[n];

  float a0 = 0.f, a1 = 0.f;
  float esum = 0.f;
  for (int c0 = 0; c0 < deg; c0 += 256) {
    int cnt = min(256, deg - c0);
    if (t < cnt) {
      int sn = src_csr[off + c0 + t];
      lds_sn[t] = sn;
      lds_s[t] = lrelu_exp(el2[sn] + ern);
    }
    __syncthreads();
    for (int p = w * 2 + half; p < cnt; p += 8) {
      int sn = lds_sn[p];
      float a = lds_s[p];
      if (hl < 24) {
        unsigned u = ((const unsigned*)feat2ph)[(size_t)sn * 24 + hl];
        a0 += a * __uint_as_float(u << 16);
        a1 += a * __uint_as_float(u & 0xFFFF0000u);
      }
      esum += a;
    }
    __syncthreads();
  }
  a0 += __shfl_down(a0, 32, 64);
  a1 += __shfl_down(a1, 32, 64);
  esum += __shfl_down(esum, 32, 64);
  if (half == 0 && hl < 24) {
    ldsacc[w][hl * 2] = a0;
    ldsacc[w][hl * 2 + 1] = a1;
  }
  if (lane == 0) ldssum[w] = esum;  // lane0 = wave partial (no wave-reduce!)
  __syncthreads();

  if (t < 64) {
    float denom = ldssum[0] + ldssum[1] + ldssum[2] + ldssum[3];
    float inv = 1.f / fmaxf(denom, 1e-9f);
    float logits = 0.f;
    if (t < OUT_FEATS)
      logits = (ldsacc[0][t] + ldsacc[1][t] + ldsacc[2][t] + ldsacc[3][t]) * inv;
    float v = (t < OUT_FEATS) ? logits : -INFINITY;
    float mx = wave_reduce_max(v);
    float ex = (t < OUT_FEATS) ? expf(logits - mx) : 0.f;
    float s = wave_reduce_sum(ex);
    if (t < OUT_FEATS) out[n * OUT_FEATS + t] = logits - mx - logf(s);
  }
}

extern "C" void kernel_launch(void* const* d_in, const int* in_sizes, int n_in,
                              void* d_out, int out_size, void* d_ws, size_t ws_size,
                              hipStream_t stream) {
  const float* features = (const float*)d_in[0];
  const int* src = (const int*)d_in[1];
  const int* dst = (const int*)d_in[2];
  const float* W1 = (const float*)d_in[3];
  const float* al1 = (const float*)d_in[4];
  const float* ar1 = (const float*)d_in[5];
  const float* W2 = (const float*)d_in[6];
  const float* al2 = (const float*)d_in[7];
  const float* ar2 = (const float*)d_in[8];
  float* out = (float*)d_out;

  char* ws = (char*)d_ws;
  size_t o = 0;
  auto alloc = [&](size_t bytes) {
    void* p = ws + o;
    o = (o + bytes + 255) & ~(size_t)255;
    return p;
  };
  unsigned short* feat1h = (unsigned short*)alloc((size_t)N_NODES * 256 * 2);
  unsigned short* h2h = (unsigned short*)alloc((size_t)N_NODES * 256 * 2);
  float* el1 = (float*)alloc((size_t)N_NODES * 4 * 4);
  float* er1 = (float*)alloc((size_t)N_NODES * 4 * 4);
  unsigned short* feat2ph = (unsigned short*)alloc((size_t)N_NODES * 48 * 2);
  float* el2v = (float*)alloc((size_t)N_NODES * 4);
  float* er2v = (float*)alloc((size_t)N_NODES * 4);
  unsigned short* W1f = (unsigned short*)alloc((size_t)256 * 256 * 2);
  unsigned short* W2f = (unsigned short*)alloc((size_t)256 * 48 * 2);
  float* wa = (float*)alloc(256 * 4);
  float* wb = (float*)alloc(256 * 4);
  int* deg = (int*)alloc((size_t)N_NODES * 4);
  int* cursor = (int*)alloc((size_t)N_NODES * 4);
  int* offsets = (int*)alloc((size_t)(N_NODES + 1) * 4);
  int* src_csr = (int*)alloc((size_t)N_EDGES * 4);

  hipMemsetAsync(deg, 0, (size_t)N_NODES * 4, stream);

  prep_kernel<<<1555, 256, 0, stream>>>(dst, deg, W1, W1f, W2, W2f, al2, ar2, wa, wb);
  gemm1_scan_kernel<<<314, 256, 0, stream>>>(features, W1f, al1, ar1, feat1h, el1, er1, deg,
                                             offsets, cursor);
  fill_kernel<<<(N_EDGES + 255) / 256, 256, 0, stream>>>(src, dst, cursor, src_csr);
  agg1_kernel<<<N_NODES, 256, 0, stream>>>(src_csr, offsets, feat1h, el1, er1, wa, wb, h2h,
                                           el2v, er2v);
  gemm2_kernel<<<(N_NODES + 63) / 64, 256, 0, stream>>>(h2h, W2f, feat2ph);
  agg2_kernel<<<N_NODES, 256, 0, stream>>>(src_csr, offsets, feat2ph, el2v, er2v, out);
}